// Round 5
// baseline (576.088 us; speedup 1.0000x reference)
//
#include <hip/hip_runtime.h>

#define HIDDEN 4096
#define INTER  11008
#define MTOK   128          // B*S
#define NMERG  (2*INTER)    // 22016
#define KS1    4            // stage-1 K-split (bf16 partials, 22.5 MB)
#define KS2    16           // stage-2 K-split (fp32 partials, 33.5 MB)

typedef short          short8  __attribute__((ext_vector_type(8)));
typedef unsigned short ushort8 __attribute__((ext_vector_type(8)));
typedef float          f32x16  __attribute__((ext_vector_type(16)));

static __device__ __forceinline__ unsigned short f2bf_rne(float f) {
    unsigned u = __builtin_bit_cast(unsigned, f);
    u += 0x7FFFu + ((u >> 16) & 1u);
    return (unsigned short)(u >> 16);
}
static __device__ __forceinline__ float bf2f(unsigned short b) {
    unsigned u = (unsigned)b << 16;
    return __builtin_bit_cast(float, u);
}
// pack two fp32 -> bf16x2 by truncation (exact for integer-valued weights)
static __device__ __forceinline__ int pk2(float lo, float hi) {
    return (int)__builtin_amdgcn_perm(__builtin_bit_cast(unsigned, hi),
                                      __builtin_bit_cast(unsigned, lo),
                                      0x07060302u);
}

// ---- x fp32 -> bf16 in MFMA A-fragment order ----
// A2[((kstep*4+ms)*64+lane)*8 + j] = bf16(x[m][k]), m=ms*32+(lane&31), k=kstep*16+(lane>>5)*8+j
__global__ void cvt_x_k(const float* __restrict__ x, unsigned short* __restrict__ A2) {
    int f = blockIdx.x * 256 + threadIdx.x;
    int lane = f & 63, w = f >> 6;
    int kstep = w >> 2, ms = w & 3;
    int m = ms * 32 + (lane & 31);
    int k = kstep * 16 + (lane >> 5) * 8;
    const float* src = x + (size_t)m * HIDDEN + k;
    float4 v0 = *(const float4*)(src);
    float4 v1 = *(const float4*)(src + 4);
    ushort8 o;
    o[0] = f2bf_rne(v0.x); o[1] = f2bf_rne(v0.y); o[2] = f2bf_rne(v0.z); o[3] = f2bf_rne(v0.w);
    o[4] = f2bf_rne(v1.x); o[5] = f2bf_rne(v1.y); o[6] = f2bf_rne(v1.z); o[7] = f2bf_rne(v1.w);
    *(ushort8*)(A2 + (size_t)f * 8) = o;
}

// ---- dequant GEMM partial, DIRECT register streaming (no LDS, no barriers) ----
// r0-r4 all plateaued at ~2.45 TB/s effective weight BW using global_load_lds,
// insensitive to burst size (r4) and pipeline depth (r3). Every proven >6 TB/s
// datapoint on gfx950 (m13) streams plain global_load into REGISTERS at high
// occupancy. So: each wave owns 32 weight rows x all 128 m; B-fragments are
// loaded directly global->VGPR (lane = row n0+(lane&31), 2 x dwordx4 per
// k16-step, perfect 64B line coverage), double-buffered 1 step ahead; A from
// the small L2-resident fragment buffer likewise double-buffered. Compiler's
// native precise vmcnt tracking handles the waits (register dests). 12
// waves/CU (launch_bounds 256,3) provide the TLP that carries latency.
template<bool OBF16>
__global__ __launch_bounds__(256, 3) void gemm_k(
    const unsigned short* __restrict__ A2,
    const float* __restrict__ B0, const float* __restrict__ B1, int nhalf,
    void* __restrict__ part, int K, int N, int stepsTot, int ksplit)
{
    const int lane = threadIdx.x & 63;
    const int ws   = threadIdx.x >> 6;
    const int wq   = blockIdx.x * 4 + ws;          // global wave task
    const int n0   = wq * 32;
    const int ks   = blockIdx.y;
    const int sbeg = (ks * stepsTot) / ksplit;     // k16-step range
    const int send = ((ks + 1) * stepsTot) / ksplit;

    const int n = n0 + (lane & 31);
    const float* rp = (n < nhalf) ? B0 + (size_t)n * K
                                  : B1 + (size_t)(n - nhalf) * K;
    const char* rb = (const char*)rp + (lane >> 5) * 32;     // this lane's half-k
    const unsigned short* ab = A2 + (size_t)lane * 8;

    f32x16 acc[4];
#pragma unroll
    for (int t = 0; t < 4; ++t)
#pragma unroll
        for (int r = 0; r < 16; ++r) acc[t][r] = 0.f;

    float4 b0[2], b1[2];
    short8 a0[4], a1[4];

    auto loadB = [&](int s, float4 (&b)[2]) {
        b[0] = *(const float4*)(rb + (size_t)s * 64);
        b[1] = *(const float4*)(rb + (size_t)s * 64 + 16);
    };
    auto loadA = [&](int s, short8 (&a)[4]) {
#pragma unroll
        for (int ms = 0; ms < 4; ++ms)
            a[ms] = *(const short8*)(ab + (size_t)(s * 4 + ms) * 64 * 8);
    };
    auto comp = [&](float4 (&b)[2], short8 (&a)[4]) {
        int4 bi;
        bi.x = pk2(b[0].x, b[0].y); bi.y = pk2(b[0].z, b[0].w);
        bi.z = pk2(b[1].x, b[1].y); bi.w = pk2(b[1].z, b[1].w);
        short8 bf = __builtin_bit_cast(short8, bi);
#pragma unroll
        for (int ms = 0; ms < 4; ++ms)
            acc[ms] = __builtin_amdgcn_mfma_f32_32x32x16_bf16(a[ms], bf, acc[ms], 0, 0, 0);
    };

    // prologue: two steps in flight
    loadB(sbeg, b0); loadA(sbeg, a0);
    if (send - sbeg > 1) { loadB(sbeg + 1, b1); loadA(sbeg + 1, a1); }

    for (int s = sbeg; s < send; s += 2) {
        comp(b0, a0);
        if (s + 2 < send) { loadB(s + 2, b0); loadA(s + 2, a0); }
        if (s + 1 < send) {
            comp(b1, a1);
            if (s + 3 < send) { loadB(s + 3, b1); loadA(s + 3, a1); }
        }
    }

    // C/D layout: col=lane&31 -> n; row=(r&3)+8*(r>>2)+4*(lane>>5) -> m
#pragma unroll
    for (int ms = 0; ms < 4; ++ms)
#pragma unroll
        for (int r = 0; r < 16; ++r) {
            int m = ms * 32 + (r & 3) + 8 * (r >> 2) + 4 * (lane >> 5);
            size_t idx = ((size_t)ks * MTOK + m) * (size_t)N + (n0 + (lane & 31));
            if (OBF16) ((unsigned short*)part)[idx] = f2bf_rne(acc[ms][r]);
            else       ((float*)part)[idx] = acc[ms][r];
        }
}

// ---- combine KS1 bf16 partials, scale, SwiGLU -> h in fragment order ----
__global__ void swiglu_k(const unsigned short* __restrict__ p1,  // [KS1][MTOK][NMERG] bf16
                         const float* __restrict__ s1, const float* __restrict__ s3,
                         unsigned short* __restrict__ h2)        // fragment-ordered, K=INTER
{
    int f = blockIdx.x * 256 + threadIdx.x;
    int lane = f & 63, w = f >> 6;
    int kstep = w >> 2, ms = w & 3;
    int m = ms * 32 + (lane & 31);
    int j = kstep * 16 + (lane >> 5) * 8;
    float up[8], gt[8];
#pragma unroll
    for (int e = 0; e < 8; ++e) { up[e] = 0.f; gt[e] = 0.f; }
#pragma unroll
    for (int ks = 0; ks < KS1; ++ks) {
        const unsigned short* pu = p1 + ((size_t)ks * MTOK + m) * NMERG + j;
        ushort8 u = *(const ushort8*)(pu);
        ushort8 g = *(const ushort8*)(pu + INTER);
#pragma unroll
        for (int e = 0; e < 8; ++e) { up[e] += bf2f(u[e]); gt[e] += bf2f(g[e]); }
    }
    float4 c1a = *(const float4*)(s1 + j), c1b = *(const float4*)(s1 + j + 4);
    float4 c3a = *(const float4*)(s3 + j), c3b = *(const float4*)(s3 + j + 4);
    float c1[8] = {c1a.x, c1a.y, c1a.z, c1a.w, c1b.x, c1b.y, c1b.z, c1b.w};
    float c3[8] = {c3a.x, c3a.y, c3a.z, c3a.w, c3b.x, c3b.y, c3b.z, c3b.w};
    ushort8 o;
#pragma unroll
    for (int e = 0; e < 8; ++e) {
        float u = up[e] * c1[e], g = gt[e] * c3[e];
        o[e] = f2bf_rne(g * u / (1.f + __expf(-u)));
    }
    *(ushort8*)(h2 + (size_t)f * 8) = o;
}

// ---- reduce KS2 fp32 partials, scale by w2_s ----
__global__ void reduce_k(const float* __restrict__ p, const float* __restrict__ s2,
                         float* __restrict__ out)
{
    int i = (blockIdx.x * 256 + threadIdx.x) * 4;
    float4 acc = *(const float4*)(p + i);
#pragma unroll
    for (int s = 1; s < KS2; ++s) {
        float4 v = *(const float4*)(p + (size_t)s * MTOK * HIDDEN + i);
        acc.x += v.x; acc.y += v.y; acc.z += v.z; acc.w += v.w;
    }
    int ncol = i & (HIDDEN - 1);
    float4 sc = *(const float4*)(s2 + ncol);
    acc.x *= sc.x; acc.y *= sc.y; acc.z *= sc.z; acc.w *= sc.w;
    *(float4*)(out + i) = acc;
}

extern "C" void kernel_launch(void* const* d_in, const int* in_sizes, int n_in,
                              void* d_out, int out_size, void* d_ws, size_t ws_size,
                              hipStream_t stream) {
    const float* x   = (const float*)d_in[0];
    const float* w1q = (const float*)d_in[1];
    const float* w1s = (const float*)d_in[2];
    const float* w3q = (const float*)d_in[3];
    const float* w3s = (const float*)d_in[4];
    const float* w2q = (const float*)d_in[5];
    const float* w2s = (const float*)d_in[6];
    float* out = (float*)d_out;

    char* ws = (char*)d_ws;
    unsigned short* xb2 = (unsigned short*)ws;                 // 1 MB   fragment-ordered x
    unsigned short* h2  = (unsigned short*)(ws + (1u << 20));  // 2.75 MB fragment-ordered h
    void* part          = (void*)(ws + (4u << 20));            // 22.5 MB bf16 / 33.5 MB fp32 partials

    // 1) x -> bf16 fragments
    cvt_x_k<<<MTOK * HIDDEN / 8 / 256, 256, 0, stream>>>(x, xb2);
    // 2) up/gate: merged [w1;w3], N=22016, K=4096 (256 k16-steps), K-split 4 -> 64 steps/wave
    gemm_k<true><<<dim3(NMERG / 128, KS1), 256, 0, stream>>>(
        xb2, w1q, w3q, INTER, part, HIDDEN, NMERG, HIDDEN / 16, KS1);
    // 3) SwiGLU -> h fragments
    swiglu_k<<<MTOK * INTER / 8 / 256, 256, 0, stream>>>(
        (const unsigned short*)part, w1s, w3s, h2);
    // 4) out: w2, N=4096, K=11008 (688 k16-steps), K-split 16 -> 43 steps/wave
    gemm_k<false><<<dim3(HIDDEN / 128, KS2), 256, 0, stream>>>(
        h2, w2q, w2q, 1 << 30, part, INTER, HIDDEN, INTER / 16, KS2);
    // 5) reduce + scale
    reduce_k<<<MTOK * HIDDEN / 4 / 256, 256, 0, stream>>>(
        (const float*)part, w2s, out);
}